// Round 4
// baseline (1020.634 us; speedup 1.0000x reference)
//
#include <hip/hip_runtime.h>
#include <stdint.h>

#define DIM   2048
#define NEXP  8
#define EDIM  1024
#define NTOK  8192   // B*S = 4*2048

using bf16x8 = __attribute__((ext_vector_type(8))) short;
using f32x4  = __attribute__((ext_vector_type(4))) float;
using u16x2  = __attribute__((ext_vector_type(2))) unsigned short;

typedef __attribute__((address_space(3))) void lds_void_t;
typedef const __attribute__((address_space(1))) void gbl_void_t;

__device__ static inline void load_lds16(const void* g, void* l) {
    __builtin_amdgcn_global_load_lds((gbl_void_t*)g, (lds_void_t*)l, 16, 0, 0);
}

// fp32 -> bf16 bits, round-to-nearest-even
__device__ static inline unsigned short f2b(float x) {
    union { float f; unsigned u; } v; v.f = x;
    unsigned r = v.u + 0x7fffu + ((v.u >> 16) & 1u);
    return (unsigned short)(r >> 16);
}

// tanh-approx gelu (matches jax.nn.gelu approximate=True)
__device__ static inline float gelu_f(float x) {
    float u = 0.7978845608028654f * x * (1.0f + 0.044715f * x * x);
    u = fminf(fmaxf(u, -15.0f), 15.0f);
    float e = __expf(2.0f * u);
    float th = (e - 1.0f) / (e + 1.0f);
    return 0.5f * x * (1.0f + th);
}

// ---------------------------------------------------------------------------
// Transpose + cast fp32 [R,C] row-major -> bf16 [C,R] row-major. 64x64 tiles.
// ---------------------------------------------------------------------------
__global__ __launch_bounds__(256)
void transpose_cast(const float* __restrict__ in, unsigned short* __restrict__ out,
                    int R, int C) {
    __shared__ float tile[64][65];
    const size_t slab = (size_t)blockIdx.z * R * C;
    in  += slab;
    out += slab;
    const int r0 = blockIdx.y * 64;
    const int c0 = blockIdx.x * 64;
    const int tx = threadIdx.x & 63;
    const int tw = threadIdx.x >> 6;
    #pragma unroll
    for (int i = 0; i < 16; ++i)
        tile[tw * 16 + i][tx] = in[(size_t)(r0 + tw * 16 + i) * C + c0 + tx];
    __syncthreads();
    const int rp = (threadIdx.x & 31) * 2;   // r-pair base (lane covers 2 rows)
    const int cy = threadIdx.x >> 5;         // 0..7
    #pragma unroll
    for (int j = 0; j < 8; ++j) {
        const int c = cy + j * 8;
        u16x2 v;
        v.x = f2b(tile[rp][c]);
        v.y = f2b(tile[rp + 1][c]);
        *(u16x2*)&out[(size_t)(c0 + c) * R + r0 + rp] = v;
    }
}

// ---------------------------------------------------------------------------
// Router + x cast: one block per token. float4 Wr loads.
// ---------------------------------------------------------------------------
__global__ __launch_bounds__(256)
void router_convert(const float* __restrict__ x, const float* __restrict__ Wr,
                    const float* __restrict__ br, unsigned short* __restrict__ xb,
                    float* __restrict__ probs) {
    const int t   = blockIdx.x;
    const int tid = threadIdx.x;
    const float* xr = x + (size_t)t * DIM;
    const float4* Wr4 = (const float4*)Wr;   // [DIM][2] float4
    float s[NEXP];
    #pragma unroll
    for (int e = 0; e < NEXP; ++e) s[e] = 0.f;
    for (int j = tid; j < DIM; j += 256) {
        float v = xr[j];
        xb[(size_t)t * DIM + j] = f2b(v);
        const float4 w0 = Wr4[j * 2];
        const float4 w1 = Wr4[j * 2 + 1];
        s[0] += v * w0.x; s[1] += v * w0.y; s[2] += v * w0.z; s[3] += v * w0.w;
        s[4] += v * w1.x; s[5] += v * w1.y; s[6] += v * w1.z; s[7] += v * w1.w;
    }
    #pragma unroll
    for (int e = 0; e < NEXP; ++e)
        #pragma unroll
        for (int off = 32; off > 0; off >>= 1) s[e] += __shfl_down(s[e], off);
    __shared__ float part[4][NEXP];
    const int wave = tid >> 6, lane = tid & 63;
    if (lane == 0) {
        #pragma unroll
        for (int e = 0; e < NEXP; ++e) part[wave][e] = s[e];
    }
    __syncthreads();
    if (tid == 0) {
        float l[NEXP], mx = -1e30f;
        #pragma unroll
        for (int e = 0; e < NEXP; ++e) {
            l[e] = part[0][e] + part[1][e] + part[2][e] + part[3][e] + br[e];
            mx = fmaxf(mx, l[e]);
        }
        float sum = 0.f;
        #pragma unroll
        for (int e = 0; e < NEXP; ++e) { l[e] = __expf(l[e] - mx); sum += l[e]; }
        const float inv = 1.f / sum;
        #pragma unroll
        for (int e = 0; e < NEXP; ++e) probs[t * NEXP + e] = l[e] * inv;
    }
}

// ---------------------------------------------------------------------------
// bf16 GEMM: C[M,N] = A[M,K] * Bt[N,K]^T
// R8 = R7 + DERIVED LGKM WAITS (the m232 "OPEN: needs derived-waits port"):
// fragment reads are issued ONE PHASE AHEAD of their consuming MFMA, and each
// phase waits a COUNTED lgkmcnt(N) (DS returns in-order per wave) instead of
// lgkmcnt(0). Every ds_read now has a full MFMA phase (~500cy) to land.
// Fragment schedule per tile (buffer bb, next buffer nb):
//   F1 = B all (8) + A rows0-1 (4)  -- issued in PREVIOUS tile's phase 4,
//        AFTER the barrier that follows all waves' VMWAIT(6) (tile resident
//        for the whole block, not just the issuing wave's loads)
//   ph1: issue F2 (A2-3 -> aB); stage; bar; lgkmcnt(4)  [F1 done]; MFMA(0,aA)
//   ph2: issue F3 (A4-5 -> aA); stage; bar; lgkmcnt(4)  [F2 done]; MFMA(2,aB)
//   ph3: issue F4 (A6-7 -> aB); stage; bar; lgkmcnt(4)  [F3 done]; MFMA(4,aA)
//   ph4: stage; VMWAIT(6); bar; issue F1'(nb) (12); lgkmcnt(12) [F4 done];
//        MFMA(6,aB)
// B-fragments ping-pong (bfr0/bfr1) since F1' lands while F_cur's B is still
// feeding MFMAs. WAR ledger (reads proven complete via counted lgkm, then >=1
// barrier before region overwrite is issued):
//   B(bb):   done @ph1-wait;  overwritten ISS2/ISS3 (ph2/3)            OK
//   A0(bb):  F1 done @ph1-wait, F2 done @ph2-wait; overwritten ISS4    OK
//   A1(bb):  F3 done @ph3-wait, F4 done @ph4-wait; overwritten next-
//            tile ISS1 (after ph4's closing barrier)                   OK
// RAW: F1'(nb) issued after barrier following all waves' VMWAIT(6)     OK
// vmcnt/staging schedule identical to R7 (proven there).
// ---------------------------------------------------------------------------
#define VMWAIT(n)   asm volatile("s_waitcnt vmcnt(" #n ")" ::: "memory")
#define LGKMWAIT(n) asm volatile("s_waitcnt lgkmcnt(" #n ")" ::: "memory")
#define SCHEDB()    __builtin_amdgcn_sched_barrier(0)
#define BARRIER()   do { asm volatile("" ::: "memory"); \
    __builtin_amdgcn_s_barrier(); asm volatile("" ::: "memory"); } while (0)
// phase sync #1: end read/stage region -> barrier -> counted lgkm wait -> MFMA
#define PS1(W) do { SCHEDB(); BARRIER(); W; SCHEDB(); } while (0)
// phase sync #2: end MFMA region -> barrier -> next phase
#define PS2()  do { SCHEDB(); BARRIER(); SCHEDB(); } while (0)

#define STAGE_A(bufc, rho, koff) do { \
    load_lds16(srcA + (size_t)((rho) * 128) * K + (koff),      dstA + (bufc) * 16384 + (rho) * 8192); \
    load_lds16(srcA + (size_t)((rho) * 128 + 64) * K + (koff), dstA + (bufc) * 16384 + (rho) * 8192 + 4096); \
} while (0)

#define STAGE_B(bufc, rho, koff) do { \
    load_lds16(srcB + (size_t)((rho) * 128) * K + (koff),      dstB + (bufc) * 16384 + (rho) * 8192); \
    load_lds16(srcB + (size_t)((rho) * 128 + 64) * K + (koff), dstB + (bufc) * 16384 + (rho) * 8192 + 4096); \
} while (0)

// asm ds_read_b128: addr VGPR (per-u swizzled base), compile-time byte offset.
#define DSR128(dst, addr, IMM) \
    asm volatile("ds_read_b128 %0, %1 offset:%2" : "=v"(dst) : "v"(addr), "n"(IMM))

#define RD_B(BF, bb) do { \
    DSR128(BF[0][0], bAddr0, (bb)*32768 + 0);    DSR128(BF[0][1], bAddr1, (bb)*32768 + 0); \
    DSR128(BF[1][0], bAddr0, (bb)*32768 + 2048); DSR128(BF[1][1], bAddr1, (bb)*32768 + 2048); \
    DSR128(BF[2][0], bAddr0, (bb)*32768 + 4096); DSR128(BF[2][1], bAddr1, (bb)*32768 + 4096); \
    DSR128(BF[3][0], bAddr0, (bb)*32768 + 6144); DSR128(BF[3][1], bAddr1, (bb)*32768 + 6144); \
} while (0)

#define RD_A2(dst, I0, bb) do { \
    DSR128(dst[0][0], aAddr0, (bb)*32768 + (I0)*2048);       DSR128(dst[0][1], aAddr1, (bb)*32768 + (I0)*2048); \
    DSR128(dst[1][0], aAddr0, (bb)*32768 + ((I0)+1)*2048);   DSR128(dst[1][1], aAddr1, (bb)*32768 + ((I0)+1)*2048); \
} while (0)

// next-tile F1 prefetch: B-all + A rows0-1 of buffer nb into BF/aA
#define RDN(BF, nb) do { RD_B(BF, nb); RD_A2(aA, 0, nb); } while (0)

#define MFMA_Q(i0, AF, BF) do { \
    __builtin_amdgcn_s_setprio(1); \
    _Pragma("unroll") for (int ii = 0; ii < 2; ++ii) \
    _Pragma("unroll") for (int u = 0; u < 2; ++u) \
    _Pragma("unroll") for (int j = 0; j < 4; ++j) \
        acc[(i0) + ii][j] = __builtin_amdgcn_mfma_f32_16x16x32_bf16(AF[ii][u], BF[j][u], acc[(i0) + ii][j], 0, 0, 0); \
    __builtin_amdgcn_s_setprio(0); \
} while (0)

#define KTILE(bb, BC, ISS1, ISS2, ISS3, ISS4, VMW, RDNEXT, W4) do { \
    /* phase 1: issue F2 (A rows2-3) */ \
    RD_A2(aB, 2, bb); \
    ISS1; \
    PS1(LGKMWAIT(4)); \
    MFMA_Q(0, aA, BC); \
    PS2(); \
    /* phase 2: issue F3 (A rows4-5) */ \
    RD_A2(aA, 4, bb); \
    ISS2; \
    PS1(LGKMWAIT(4)); \
    MFMA_Q(2, aB, BC); \
    PS2(); \
    /* phase 3: issue F4 (A rows6-7) */ \
    RD_A2(aB, 6, bb); \
    ISS3; \
    PS1(LGKMWAIT(4)); \
    MFMA_Q(4, aA, BC); \
    PS2(); \
    /* phase 4: stage, vm-wait, barrier, next-tile F1 prefetch */ \
    ISS4; \
    VMW; \
    SCHEDB(); BARRIER(); \
    RDNEXT; \
    W4; \
    SCHEDB(); \
    MFMA_Q(6, aB, BC); \
    PS2(); \
} while (0)

template <int MODE>
__global__ __launch_bounds__(512, 2)
void gemm_bt(const unsigned short* __restrict__ A,
             const unsigned short* __restrict__ Bt,
             int M, int N, int K,
             const float* __restrict__ probs,
             const float* __restrict__ bias,
             const float* __restrict__ xres,
             void* __restrict__ Cout)
{
    __shared__ unsigned short As[2][16384];   // [buf][256 rows x 64 cols]
    __shared__ unsigned short Bs[2][16384];

    const int tid  = threadIdx.x;
    const int wave = tid >> 6;
    const int lane = tid & 63;
    const int wm   = wave >> 2;        // 0..1  (M split)
    const int wn   = wave & 3;         // 0..3  (N split)
    const int m    = lane & 15;
    const int q    = lane >> 4;
    const int xsw  = m & 7;

    // XCD-aware bijective swizzle (both grids here are multiples of 8)
    const int nwg = gridDim.x * gridDim.y;
    int bid = blockIdx.y * gridDim.x + blockIdx.x;
    if (!(nwg & 7)) bid = (bid & 7) * (nwg >> 3) + (bid >> 3);
    const int row0 = (bid / gridDim.x) * 256;
    const int col0 = (bid % gridDim.x) * 256;

    // staging: thread handles slots g = s*512 + tid per half-tile region.
    // r = s*64 + (tid>>3); chunk kc = (tid&7) ^ (r&7) = (tid&7) ^ ((tid>>3)&7)
    const int rloc = tid >> 3;
    const int kc   = (tid & 7) ^ (rloc & 7);
    const unsigned short* srcA = A  + (size_t)(row0 + rloc) * K + kc * 8;
    const unsigned short* srcB = Bt + (size_t)(col0 + rloc) * K + kc * 8;
    unsigned short* dstA = &As[0][0] + tid * 8;
    unsigned short* dstB = &Bs[0][0] + tid * 8;

    // fragment LDS byte addresses (swizzled chunk = c ^ (row&7), row&7 == m&7)
    const int arow = (wm * 128 + m) * 64;
    const int brow = (wn * 64  + m) * 64;
    int ko[2];
    #pragma unroll
    for (int u = 0; u < 2; ++u) ko[u] = ((u * 4 + q) ^ xsw) * 8;
    const unsigned ldsAbase = (unsigned)(uintptr_t)&As[0][0];
    const unsigned ldsBbase = (unsigned)(uintptr_t)&Bs[0][0];
    const unsigned aAddr0 = ldsAbase + (unsigned)((arow + ko[0]) * 2);
    const unsigned aAddr1 = ldsAbase + (unsigned)((arow + ko[1]) * 2);
    const unsigned bAddr0 = ldsBbase + (unsigned)((brow + ko[0]) * 2);
    const unsigned bAddr1 = ldsBbase + (unsigned)((brow + ko[1]) * 2);

    f32x4 acc[8][4];
    #pragma unroll
    for (int i = 0; i < 8; ++i)
        #pragma unroll
        for (int j = 0; j < 4; ++j)
            acc[i][j] = (f32x4){0.f, 0.f, 0.f, 0.f};

    // fragment registers: B ping-pong (F1' lands while current B still in use)
    bf16x8 bfr0[4][2], bfr1[4][2], aA[2][2], aB[2][2];

    const int NT = K >> 6;   // 32 (GEMM1) / 128 (GEMM2), always even, >= 4

    // prologue: issue T0{B0,B1,A0,A1}, T1{B0,B1,A0}; keep T1's 3 newest in flight
    STAGE_B(0, 0, 0);  STAGE_B(0, 1, 0);  STAGE_A(0, 0, 0);  STAGE_A(0, 1, 0);
    STAGE_B(1, 0, 64); STAGE_B(1, 1, 64); STAGE_A(1, 0, 64);
    VMWAIT(6);
    SCHEDB(); BARRIER();
    RDN(bfr0, 0);          // tile0 F1 in flight; first phase waits lgkmcnt(4)
    SCHEDB();

    // main loop: tiles (t, t+1); issues reference tiles t+1..t+3 (<= NT-1)
    for (int t = 0; t + 3 < NT; t += 2) {
        const size_t k1 = (size_t)(t + 1) * 64;
        const size_t k2 = (size_t)(t + 2) * 64;
        const size_t k3 = (size_t)(t + 3) * 64;
        KTILE(0, bfr0, STAGE_A(1, 1, k1), STAGE_B(0, 0, k2), STAGE_B(0, 1, k2),
              STAGE_A(0, 0, k2), VMWAIT(6), RDN(bfr1, 1), LGKMWAIT(12));
        KTILE(1, bfr1, STAGE_A(0, 1, k2), STAGE_B(1, 0, k3), STAGE_B(1, 1, k3),
              STAGE_A(1, 0, k3), VMWAIT(6), RDN(bfr0, 0), LGKMWAIT(12));
    }
    // peeled tail: tile NT-2 finishes tile NT-1's staging, then drains
    {
        const size_t kl = (size_t)(NT - 1) * 64;
        KTILE(0, bfr0, STAGE_A(1, 1, kl), (void)0, (void)0, (void)0,
              VMWAIT(0), RDN(bfr1, 1), LGKMWAIT(12));
        KTILE(1, bfr1, (void)0, (void)0, (void)0, (void)0,
              (void)0, (void)0, LGKMWAIT(0));
    }

    // C/D layout (m89-verified): col = lane&15, row = (lane>>4)*4 + reg
    if (MODE == 1) {
        unsigned short* H = (unsigned short*)Cout;
        const int e = col0 >> 10;   // 256-wide tile never crosses an expert boundary
        float bv[4];
        #pragma unroll
        for (int j = 0; j < 4; ++j) bv[j] = bias[col0 + wn * 64 + j * 16 + m];
        #pragma unroll
        for (int i = 0; i < 8; ++i) {
            #pragma unroll
            for (int r = 0; r < 4; ++r) {
                const int rowg = row0 + wm * 128 + i * 16 + q * 4 + r;
                const float p = probs[rowg * NEXP + e];
                #pragma unroll
                for (int j = 0; j < 4; ++j) {
                    const int colg = col0 + wn * 64 + j * 16 + m;
                    float v = acc[i][j][r] + bv[j];   // bu flat index = e*1024+f = colg
                    H[(size_t)rowg * N + colg] = f2b(gelu_f(v) * p);
                }
            }
        }
    } else {
        float* O = (float*)Cout;
        float bdv[4][NEXP];
        #pragma unroll
        for (int j = 0; j < 4; ++j) {
            const int colg = col0 + wn * 64 + j * 16 + m;
            #pragma unroll
            for (int e = 0; e < NEXP; ++e) bdv[j][e] = bias[e * DIM + colg];
        }
        #pragma unroll
        for (int i = 0; i < 8; ++i) {
            #pragma unroll
            for (int r = 0; r < 4; ++r) {
                const int rowg = row0 + wm * 128 + i * 16 + q * 4 + r;
                float p[NEXP];
                *(float4*)&p[0] = *(const float4*)&probs[rowg * NEXP];
                *(float4*)&p[4] = *(const float4*)&probs[rowg * NEXP + 4];
                #pragma unroll
                for (int j = 0; j < 4; ++j) {
                    const int colg = col0 + wn * 64 + j * 16 + m;
                    float v = acc[i][j][r];
                    #pragma unroll
                    for (int e = 0; e < NEXP; ++e) v += p[e] * bdv[j][e];
                    v += xres[(size_t)rowg * DIM + colg];
                    O[(size_t)rowg * N + colg] = v;
                }
            }
        }
    }
}

// ---------------------------------------------------------------------------
// Workspace layout (bytes):
//   xb    bf16 [8192,2048]        @ 0          (33554432)
//   WuT   bf16 [8][1024,2048]     @ 33554432   (33554432)
//   WdT   bf16 [2048,8192]        @ 67108864   (33554432)
//   probs fp32 [8192,8]           @ 100663296  (262144)
//   h     bf16 [8192,8192]        @ 100925440  (134217728)
// ---------------------------------------------------------------------------
extern "C" void kernel_launch(void* const* d_in, const int* in_sizes, int n_in,
                              void* d_out, int out_size, void* d_ws, size_t ws_size,
                              hipStream_t stream) {
    const float* x  = (const float*)d_in[0];
    const float* Wr = (const float*)d_in[1];
    const float* br = (const float*)d_in[2];
    const float* Wu = (const float*)d_in[3];
    const float* bu = (const float*)d_in[4];
    const float* Wd = (const float*)d_in[5];
    const float* bd = (const float*)d_in[6];
    float* out = (float*)d_out;

    char* ws = (char*)d_ws;
    unsigned short* xb    = (unsigned short*)(ws);
    unsigned short* WuT   = (unsigned short*)(ws + 33554432);
    unsigned short* WdT   = (unsigned short*)(ws + 67108864);
    float*          probs = (float*)(ws + 100663296);
    unsigned short* h     = (unsigned short*)(ws + 100925440);

    // Wu [e][2048][1024] -> WuT [e][1024][2048]
    transpose_cast<<<dim3(EDIM / 64, DIM / 64, NEXP), 256, 0, stream>>>(Wu, WuT, DIM, EDIM);
    // Wd [8192][2048] -> WdT [2048][8192]
    transpose_cast<<<dim3(DIM / 64, (NEXP * EDIM) / 64, 1), 256, 0, stream>>>(Wd, WdT, NEXP * EDIM, DIM);
    // router softmax + x -> bf16
    router_convert<<<NTOK, 256, 0, stream>>>(x, Wr, br, xb, probs);
    // GEMM1: h = bf16( probs_e * gelu(x @ Wu + bu) )   M=8192 N=8192 K=2048
    gemm_bt<1><<<dim3((NEXP * EDIM) / 256, NTOK / 256), 512, 0, stream>>>(
        xb, WuT, NTOK, NEXP * EDIM, DIM, probs, bu, nullptr, h);
    // GEMM2: out = h @ Wd_concat + probs@bd + x        M=8192 N=2048 K=8192
    gemm_bt<2><<<dim3(DIM / 256, NTOK / 256), 512, 0, stream>>>(
        h, WdT, NTOK, DIM, NEXP * EDIM, probs, bd, x, out);
}

// Round 5
// 739.716 us; speedup vs baseline: 1.3798x; 1.3798x over previous
//
#include <hip/hip_runtime.h>
#include <stdint.h>

#define DIM   2048
#define NEXP  8
#define EDIM  1024
#define NTOK  8192   // B*S = 4*2048

using bf16x8 = __attribute__((ext_vector_type(8))) short;
using f32x4  = __attribute__((ext_vector_type(4))) float;
using u16x2  = __attribute__((ext_vector_type(2))) unsigned short;

typedef __attribute__((address_space(3))) void lds_void_t;
typedef const __attribute__((address_space(1))) void gbl_void_t;

__device__ static inline void load_lds16(const void* g, void* l) {
    __builtin_amdgcn_global_load_lds((gbl_void_t*)g, (lds_void_t*)l, 16, 0, 0);
}

// fp32 -> bf16 bits, round-to-nearest-even
__device__ static inline unsigned short f2b(float x) {
    union { float f; unsigned u; } v; v.f = x;
    unsigned r = v.u + 0x7fffu + ((v.u >> 16) & 1u);
    return (unsigned short)(r >> 16);
}

// tanh-approx gelu (matches jax.nn.gelu approximate=True)
__device__ static inline float gelu_f(float x) {
    float u = 0.7978845608028654f * x * (1.0f + 0.044715f * x * x);
    u = fminf(fmaxf(u, -15.0f), 15.0f);
    float e = __expf(2.0f * u);
    float th = (e - 1.0f) / (e + 1.0f);
    return 0.5f * x * (1.0f + th);
}

// ---------------------------------------------------------------------------
// Transpose + cast fp32 [R,C] row-major -> bf16 [C,R] row-major. 64x64 tiles.
// ---------------------------------------------------------------------------
__global__ __launch_bounds__(256)
void transpose_cast(const float* __restrict__ in, unsigned short* __restrict__ out,
                    int R, int C) {
    __shared__ float tile[64][65];
    const size_t slab = (size_t)blockIdx.z * R * C;
    in  += slab;
    out += slab;
    const int r0 = blockIdx.y * 64;
    const int c0 = blockIdx.x * 64;
    const int tx = threadIdx.x & 63;
    const int tw = threadIdx.x >> 6;
    #pragma unroll
    for (int i = 0; i < 16; ++i)
        tile[tw * 16 + i][tx] = in[(size_t)(r0 + tw * 16 + i) * C + c0 + tx];
    __syncthreads();
    const int rp = (threadIdx.x & 31) * 2;   // r-pair base (lane covers 2 rows)
    const int cy = threadIdx.x >> 5;         // 0..7
    #pragma unroll
    for (int j = 0; j < 8; ++j) {
        const int c = cy + j * 8;
        u16x2 v;
        v.x = f2b(tile[rp][c]);
        v.y = f2b(tile[rp + 1][c]);
        *(u16x2*)&out[(size_t)(c0 + c) * R + r0 + rp] = v;
    }
}

// ---------------------------------------------------------------------------
// Router + x cast: one block per token. float4 Wr loads.
// ---------------------------------------------------------------------------
__global__ __launch_bounds__(256)
void router_convert(const float* __restrict__ x, const float* __restrict__ Wr,
                    const float* __restrict__ br, unsigned short* __restrict__ xb,
                    float* __restrict__ probs) {
    const int t   = blockIdx.x;
    const int tid = threadIdx.x;
    const float* xr = x + (size_t)t * DIM;
    const float4* Wr4 = (const float4*)Wr;   // [DIM][2] float4
    float s[NEXP];
    #pragma unroll
    for (int e = 0; e < NEXP; ++e) s[e] = 0.f;
    for (int j = tid; j < DIM; j += 256) {
        float v = xr[j];
        xb[(size_t)t * DIM + j] = f2b(v);
        const float4 w0 = Wr4[j * 2];
        const float4 w1 = Wr4[j * 2 + 1];
        s[0] += v * w0.x; s[1] += v * w0.y; s[2] += v * w0.z; s[3] += v * w0.w;
        s[4] += v * w1.x; s[5] += v * w1.y; s[6] += v * w1.z; s[7] += v * w1.w;
    }
    #pragma unroll
    for (int e = 0; e < NEXP; ++e)
        #pragma unroll
        for (int off = 32; off > 0; off >>= 1) s[e] += __shfl_down(s[e], off);
    __shared__ float part[4][NEXP];
    const int wave = tid >> 6, lane = tid & 63;
    if (lane == 0) {
        #pragma unroll
        for (int e = 0; e < NEXP; ++e) part[wave][e] = s[e];
    }
    __syncthreads();
    if (tid == 0) {
        float l[NEXP], mx = -1e30f;
        #pragma unroll
        for (int e = 0; e < NEXP; ++e) {
            l[e] = part[0][e] + part[1][e] + part[2][e] + part[3][e] + br[e];
            mx = fmaxf(mx, l[e]);
        }
        float sum = 0.f;
        #pragma unroll
        for (int e = 0; e < NEXP; ++e) { l[e] = __expf(l[e] - mx); sum += l[e]; }
        const float inv = 1.f / sum;
        #pragma unroll
        for (int e = 0; e < NEXP; ++e) probs[t * NEXP + e] = l[e] * inv;
    }
}

// ---------------------------------------------------------------------------
// bf16 GEMM: C[M,N] = A[M,K] * Bt[N,K]^T
// R9 = R7 structure (KTILE-local fragments — reverts R8's spill: WRITE_SIZE
// 627MB->131MB) with ALL "memory" clobbers removed from wait/barrier asm.
// Why: R5-R8 all plateau at the m233 "2-phase drain" level regardless of
// schedule detail. Cause: memory-clobbered asm looks like a potential LDS
// reader to SIInsertWaitcnts; with LDS-DMA (global_load_lds) outstanding it
// inserts vmcnt(0) before EVERY such asm -> every barrier was a hidden full
// drain, so the counted vmcnt(6) pipeline never existed. The m201 template's
// literal idiom is raw __builtin_amdgcn_s_barrier() + asm volatile waits with
// NO clobber; ordering is carried by sched_barrier(0) (side-effecting
// intrinsic — blocks code motion without looking like a memory access).
// Hazard ledger (unchanged from R7, re-audited):
//   vmcnt(6) at ph4 retires exactly the 8 loads covering the buffer the next
//     KTILE reads (3 half-tile groups = 6 loads stay in flight).
//   B frags read ph1, drained ph1-lgkm0 -> region overwritten ISS2/3 (ph2/3);
//   A rows 0-5 read ph1/2, drained in-phase -> overwritten ISS4 (ph4);
//   A rows 6-7 read ph3, drained ph3-lgkm0 -> overwritten next-tile ISS1.
//   Every overwrite issues >=1 barrier after its region's reads drained.
// ---------------------------------------------------------------------------
#define VMWAIT(n)   asm volatile("s_waitcnt vmcnt(" #n ")")
#define LGKM0()     asm volatile("s_waitcnt lgkmcnt(0)")
#define SCHEDB()    __builtin_amdgcn_sched_barrier(0)
// phase sync #1: end read/stage region -> barrier -> drain LDS reads -> MFMA
#define PHASE_SYNC1() do { SCHEDB(); __builtin_amdgcn_s_barrier(); \
    LGKM0(); SCHEDB(); } while (0)
// phase sync #2: end MFMA region -> barrier -> next phase
#define PHASE_SYNC2() do { SCHEDB(); __builtin_amdgcn_s_barrier(); \
    SCHEDB(); } while (0)

#define STAGE_A(bufc, rho, koff) do { \
    load_lds16(srcA + (size_t)((rho) * 128) * K + (koff),      dstA + (bufc) * 16384 + (rho) * 8192); \
    load_lds16(srcA + (size_t)((rho) * 128 + 64) * K + (koff), dstA + (bufc) * 16384 + (rho) * 8192 + 4096); \
} while (0)

#define STAGE_B(bufc, rho, koff) do { \
    load_lds16(srcB + (size_t)((rho) * 128) * K + (koff),      dstB + (bufc) * 16384 + (rho) * 8192); \
    load_lds16(srcB + (size_t)((rho) * 128 + 64) * K + (koff), dstB + (bufc) * 16384 + (rho) * 8192 + 4096); \
} while (0)

// asm ds_read_b128: addr VGPR (per-u swizzled base), compile-time byte offset.
#define DSR128(dst, addr, IMM) \
    asm volatile("ds_read_b128 %0, %1 offset:%2" : "=v"(dst) : "v"(addr), "n"(IMM))

#define RD_B(bb) do { \
    DSR128(bfr[0][0], bAddr0, (bb)*32768 + 0);    DSR128(bfr[0][1], bAddr1, (bb)*32768 + 0); \
    DSR128(bfr[1][0], bAddr0, (bb)*32768 + 2048); DSR128(bfr[1][1], bAddr1, (bb)*32768 + 2048); \
    DSR128(bfr[2][0], bAddr0, (bb)*32768 + 4096); DSR128(bfr[2][1], bAddr1, (bb)*32768 + 4096); \
    DSR128(bfr[3][0], bAddr0, (bb)*32768 + 6144); DSR128(bfr[3][1], bAddr1, (bb)*32768 + 6144); \
} while (0)

#define RD_A2(dst, I0, bb) do { \
    DSR128(dst[0][0], aAddr0, (bb)*32768 + (I0)*2048);       DSR128(dst[0][1], aAddr1, (bb)*32768 + (I0)*2048); \
    DSR128(dst[1][0], aAddr0, (bb)*32768 + ((I0)+1)*2048);   DSR128(dst[1][1], aAddr1, (bb)*32768 + ((I0)+1)*2048); \
} while (0)

#define MFMA_Q(i0, AF) do { \
    __builtin_amdgcn_s_setprio(1); \
    _Pragma("unroll") for (int ii = 0; ii < 2; ++ii) \
    _Pragma("unroll") for (int u = 0; u < 2; ++u) \
    _Pragma("unroll") for (int j = 0; j < 4; ++j) \
        acc[(i0) + ii][j] = __builtin_amdgcn_mfma_f32_16x16x32_bf16(AF[ii][u], bfr[j][u], acc[(i0) + ii][j], 0, 0, 0); \
    __builtin_amdgcn_s_setprio(0); \
} while (0)

#define KTILE(bb, ISS1, ISS2, ISS3, ISS4, VMW) do { \
    bf16x8 bfr[4][2], aA[2][2], aB[2][2]; \
    /* phase 1: 12 ds_read (B all + A rows 0-1) */ \
    RD_B(bb); RD_A2(aA, 0, bb); \
    ISS1; \
    PHASE_SYNC1(); \
    MFMA_Q(0, aA); \
    PHASE_SYNC2(); \
    /* phase 2: 8 ds_read (A rows 2-3 -> aB, rows 4-5 -> aA) */ \
    RD_A2(aB, 2, bb); RD_A2(aA, 4, bb); \
    ISS2; \
    PHASE_SYNC1(); \
    MFMA_Q(2, aB); \
    PHASE_SYNC2(); \
    /* phase 3: 4 ds_read (A rows 6-7 -> aB) */ \
    RD_A2(aB, 6, bb); \
    ISS3; \
    PHASE_SYNC1(); \
    MFMA_Q(4, aA); \
    PHASE_SYNC2(); \
    /* phase 4: no reads */ \
    ISS4; \
    SCHEDB(); \
    VMW; \
    PHASE_SYNC1(); \
    MFMA_Q(6, aB); \
    PHASE_SYNC2(); \
} while (0)

template <int MODE>
__global__ __launch_bounds__(512, 2)
void gemm_bt(const unsigned short* __restrict__ A,
             const unsigned short* __restrict__ Bt,
             int M, int N, int K,
             const float* __restrict__ probs,
             const float* __restrict__ bias,
             const float* __restrict__ xres,
             void* __restrict__ Cout)
{
    __shared__ unsigned short As[2][16384];   // [buf][256 rows x 64 cols]
    __shared__ unsigned short Bs[2][16384];

    const int tid  = threadIdx.x;
    const int wave = tid >> 6;
    const int lane = tid & 63;
    const int wm   = wave >> 2;        // 0..1  (M split)
    const int wn   = wave & 3;         // 0..3  (N split)
    const int m    = lane & 15;
    const int q    = lane >> 4;
    const int xsw  = m & 7;

    // XCD-aware bijective swizzle (both grids here are multiples of 8)
    const int nwg = gridDim.x * gridDim.y;
    int bid = blockIdx.y * gridDim.x + blockIdx.x;
    if (!(nwg & 7)) bid = (bid & 7) * (nwg >> 3) + (bid >> 3);
    const int row0 = (bid / gridDim.x) * 256;
    const int col0 = (bid % gridDim.x) * 256;

    // staging: thread handles slots g = s*512 + tid per half-tile region.
    // r = s*64 + (tid>>3); chunk kc = (tid&7) ^ (r&7) = (tid&7) ^ ((tid>>3)&7)
    const int rloc = tid >> 3;
    const int kc   = (tid & 7) ^ (rloc & 7);
    const unsigned short* srcA = A  + (size_t)(row0 + rloc) * K + kc * 8;
    const unsigned short* srcB = Bt + (size_t)(col0 + rloc) * K + kc * 8;
    unsigned short* dstA = &As[0][0] + tid * 8;
    unsigned short* dstB = &Bs[0][0] + tid * 8;

    // fragment LDS byte addresses (swizzled chunk = c ^ (row&7), row&7 == m&7)
    const int arow = (wm * 128 + m) * 64;
    const int brow = (wn * 64  + m) * 64;
    int ko[2];
    #pragma unroll
    for (int u = 0; u < 2; ++u) ko[u] = ((u * 4 + q) ^ xsw) * 8;
    const unsigned ldsAbase = (unsigned)(uintptr_t)&As[0][0];
    const unsigned ldsBbase = (unsigned)(uintptr_t)&Bs[0][0];
    const unsigned aAddr0 = ldsAbase + (unsigned)((arow + ko[0]) * 2);
    const unsigned aAddr1 = ldsAbase + (unsigned)((arow + ko[1]) * 2);
    const unsigned bAddr0 = ldsBbase + (unsigned)((brow + ko[0]) * 2);
    const unsigned bAddr1 = ldsBbase + (unsigned)((brow + ko[1]) * 2);

    f32x4 acc[8][4];
    #pragma unroll
    for (int i = 0; i < 8; ++i)
        #pragma unroll
        for (int j = 0; j < 4; ++j)
            acc[i][j] = (f32x4){0.f, 0.f, 0.f, 0.f};

    const int NT = K >> 6;   // 32 (GEMM1) / 128 (GEMM2), always even, >= 4

    // prologue: issue T0{B0,B1,A0,A1}, T1{B0,B1,A0}; keep T1's 3 newest in flight
    STAGE_B(0, 0, 0);  STAGE_B(0, 1, 0);  STAGE_A(0, 0, 0);  STAGE_A(0, 1, 0);
    STAGE_B(1, 0, 64); STAGE_B(1, 1, 64); STAGE_A(1, 0, 64);
    SCHEDB();
    VMWAIT(6);
    SCHEDB();
    __builtin_amdgcn_s_barrier();
    SCHEDB();

    // main loop: tiles (t, t+1); issues reference tiles t+1..t+3 (<= NT-1)
    for (int t = 0; t + 3 < NT; t += 2) {
        const size_t k1 = (size_t)(t + 1) * 64;
        const size_t k2 = (size_t)(t + 2) * 64;
        const size_t k3 = (size_t)(t + 3) * 64;
        KTILE(0, STAGE_A(1, 1, k1), STAGE_B(0, 0, k2), STAGE_B(0, 1, k2), STAGE_A(0, 0, k2), VMWAIT(6));
        KTILE(1, STAGE_A(0, 1, k2), STAGE_B(1, 0, k3), STAGE_B(1, 1, k3), STAGE_A(1, 0, k3), VMWAIT(6));
    }
    // peeled tail: tile NT-2 finishes tile NT-1's staging, then drains
    {
        const size_t kl = (size_t)(NT - 1) * 64;
        KTILE(0, STAGE_A(1, 1, kl), (void)0, (void)0, (void)0, VMWAIT(0));
        KTILE(1, (void)0, (void)0, (void)0, (void)0, (void)0);
    }

    // C/D layout (m89-verified): col = lane&15, row = (lane>>4)*4 + reg
    if (MODE == 1) {
        unsigned short* H = (unsigned short*)Cout;
        const int e = col0 >> 10;   // 256-wide tile never crosses an expert boundary
        float bv[4];
        #pragma unroll
        for (int j = 0; j < 4; ++j) bv[j] = bias[col0 + wn * 64 + j * 16 + m];
        #pragma unroll
        for (int i = 0; i < 8; ++i) {
            #pragma unroll
            for (int r = 0; r < 4; ++r) {
                const int rowg = row0 + wm * 128 + i * 16 + q * 4 + r;
                const float p = probs[rowg * NEXP + e];
                #pragma unroll
                for (int j = 0; j < 4; ++j) {
                    const int colg = col0 + wn * 64 + j * 16 + m;
                    float v = acc[i][j][r] + bv[j];   // bu flat index = e*1024+f = colg
                    H[(size_t)rowg * N + colg] = f2b(gelu_f(v) * p);
                }
            }
        }
    } else {
        float* O = (float*)Cout;
        float bdv[4][NEXP];
        #pragma unroll
        for (int j = 0; j < 4; ++j) {
            const int colg = col0 + wn * 64 + j * 16 + m;
            #pragma unroll
            for (int e = 0; e < NEXP; ++e) bdv[j][e] = bias[e * DIM + colg];
        }
        #pragma unroll
        for (int i = 0; i < 8; ++i) {
            #pragma unroll
            for (int r = 0; r < 4; ++r) {
                const int rowg = row0 + wm * 128 + i * 16 + q * 4 + r;
                float p[NEXP];
                *(float4*)&p[0] = *(const float4*)&probs[rowg * NEXP];
                *(float4*)&p[4] = *(const float4*)&probs[rowg * NEXP + 4];
                #pragma unroll
                for (int j = 0; j < 4; ++j) {
                    const int colg = col0 + wn * 64 + j * 16 + m;
                    float v = acc[i][j][r];
                    #pragma unroll
                    for (int e = 0; e < NEXP; ++e) v += p[e] * bdv[j][e];
                    v += xres[(size_t)rowg * DIM + colg];
                    O[(size_t)rowg * N + colg] = v;
                }
            }
        }
    }
}

// ---------------------------------------------------------------------------
// Workspace layout (bytes):
//   xb    bf16 [8192,2048]        @ 0          (33554432)
//   WuT   bf16 [8][1024,2048]     @ 33554432   (33554432)
//   WdT   bf16 [2048,8192]        @ 67108864   (33554432)
//   probs fp32 [8192,8]           @ 100663296  (262144)
//   h     bf16 [8192,8192]        @ 100925440  (134217728)
// ---------------------------------------------------------------------------
extern "C" void kernel_launch(void* const* d_in, const int* in_sizes, int n_in,
                              void* d_out, int out_size, void* d_ws, size_t ws_size,
                              hipStream_t stream) {
    const float* x  = (const float*)d_in[0];
    const float* Wr = (const float*)d_in[1];
    const float* br = (const float*)d_in[2];
    const float* Wu = (const float*)d_in[3];
    const float* bu = (const float*)d_in[4];
    const float* Wd = (const float*)d_in[5];
    const float* bd = (const float*)d_in[6];
    float* out = (float*)d_out;

    char* ws = (char*)d_ws;
    unsigned short* xb    = (unsigned short*)(ws);
    unsigned short* WuT   = (unsigned short*)(ws + 33554432);
    unsigned short* WdT   = (unsigned short*)(ws + 67108864);
    float*          probs = (float*)(ws + 100663296);
    unsigned short* h     = (unsigned short*)(ws + 100925440);

    // Wu [e][2048][1024] -> WuT [e][1024][2048]
    transpose_cast<<<dim3(EDIM / 64, DIM / 64, NEXP), 256, 0, stream>>>(Wu, WuT, DIM, EDIM);
    // Wd [8192][2048] -> WdT [2048][8192]
    transpose_cast<<<dim3(DIM / 64, (NEXP * EDIM) / 64, 1), 256, 0, stream>>>(Wd, WdT, NEXP * EDIM, DIM);
    // router softmax + x -> bf16
    router_convert<<<NTOK, 256, 0, stream>>>(x, Wr, br, xb, probs);
    // GEMM1: h = bf16( probs_e * gelu(x @ Wu + bu) )   M=8192 N=8192 K=2048
    gemm_bt<1><<<dim3((NEXP * EDIM) / 256, NTOK / 256), 512, 0, stream>>>(
        xb, WuT, NTOK, NEXP * EDIM, DIM, probs, bu, nullptr, h);
    // GEMM2: out = h @ Wd_concat + probs@bd + x        M=8192 N=2048 K=8192
    gemm_bt<2><<<dim3(DIM / 256, NTOK / 256), 512, 0, stream>>>(
        h, WdT, NTOK, DIM, NEXP * EDIM, probs, bd, x, out);
}